// Round 1
// baseline (9815.408 us; speedup 1.0000x reference)
//
#include <hip/hip_runtime.h>
#include <math.h>

#define B_DIM 256
#define T_DIM 365
#define I_DIM 32
#define H_DIM 256
#define S_DIM 27
#define L_DIM 7
#define FL_DIM 56      // F*L
#define G3 768         // 3*H
#define K_DIM 288      // I + H (same for both layers: layer1 input is projected to I=32)

__device__ __forceinline__ float fast_rcp(float x) { return __builtin_amdgcn_rcpf(x); }
__device__ __forceinline__ float sigm(float x) { return fast_rcp(1.0f + __expf(-x)); }
__device__ __forceinline__ float tanh_fast(float x) { return 1.0f - 2.0f * fast_rcp(1.0f + __expf(2.0f * x)); }

// WT[k][g] = k<32 ? Wdg[g][k] : Whg[g][k-32]   (pre-transposed+concatenated recurrent weights)
__global__ void k_cat_transpose(const float* __restrict__ Wdg, const float* __restrict__ Whg,
                                float* __restrict__ WT) {
    int idx = blockIdx.x * 256 + threadIdx.x;        // over 288*768
    if (idx >= K_DIM * G3) return;
    int k = idx / G3, g = idx % G3;
    WT[idx] = (k < I_DIM) ? Wdg[g * I_DIM + k] : Whg[g * H_DIM + (k - I_DIM)];
}

// generic transpose: in [M][N] row-major -> out [N][M]
__global__ void k_transpose(const float* __restrict__ in, float* __restrict__ out, int M, int N) {
    int idx = blockIdx.x * 256 + threadIdx.x;
    if (idx >= M * N) return;
    int n = idx / M, m = idx % M;
    out[idx] = in[m * N + n];
}

// ig[b][h] = sigmoid(bsh[h] + sum_s static[b][s]*Wsh[h][s])
__global__ void k_igate(const float* __restrict__ st, const float* __restrict__ Wsh,
                        const float* __restrict__ bsh, float* __restrict__ ig) {
    __shared__ float s[S_DIM];
    int b = blockIdx.x, h = threadIdx.x;
    if (h < S_DIM) s[h] = st[b * S_DIM + h];
    __syncthreads();
    float a = bsh[h];
    for (int k = 0; k < S_DIM; ++k) a += s[k] * Wsh[h * S_DIM + k];
    ig[b * H_DIM + h] = sigm(a);
}

// Persistent per-row-pair kernel: each block owns batch rows {2b, 2b+1} and runs the whole
// T loop for both EA-LSTM layers + projection + output heads. Zero inter-block deps.
__global__ __launch_bounds__(256) void k_main(
    const float* __restrict__ x, const float* __restrict__ future,
    const float* __restrict__ WT0, const float* __restrict__ WT1,
    const float* __restrict__ bdg0, const float* __restrict__ bdg1,
    const float* __restrict__ ig0, const float* __restrict__ ig1,
    const float* __restrict__ WpT, const float* __restrict__ bp0,
    const float* __restrict__ Wh1T, const float* __restrict__ bh1,
    const float* __restrict__ Wh2, const float* __restrict__ bh2,
    const float* __restrict__ Wf1T, const float* __restrict__ bf1,
    const float* __restrict__ Wf2, const float* __restrict__ bf2,
    float* __restrict__ out) {
    __shared__ float xh0[2][K_DIM];   // [x_t | h0] per row
    __shared__ float xh1[2][K_DIM];   // [inp1_t | h1] per row
    __shared__ float pbuf[4][64];
    __shared__ float hidA[2][H_DIM];
    __shared__ float hidB[2][H_DIM];
    __shared__ float futs[2][FL_DIM];

    const int t = threadIdx.x;            // hidden column owned by this thread
    const int r0 = blockIdx.x * 2;

    for (int j = t; j < 2 * K_DIM; j += 256) { ((float*)xh0)[j] = 0.f; ((float*)xh1)[j] = 0.f; }
    __syncthreads();
    if (t < 64) { int row = t >> 5, i = t & 31; xh0[row][i] = x[(r0 + row) * (T_DIM * I_DIM) + i]; }

    const float l0bf = bdg0[t], l0bo = bdg0[256 + t], l0bg = bdg0[512 + t];
    const float l1bf = bdg1[t], l1bo = bdg1[256 + t], l1bg = bdg1[512 + t];
    const float ig00 = ig0[(r0 + 0) * H_DIM + t], ig01 = ig0[(r0 + 1) * H_DIM + t];
    const float ig10 = ig1[(r0 + 0) * H_DIM + t], ig11 = ig1[(r0 + 1) * H_DIM + t];
    float c00 = 0.f, c01 = 0.f, c10 = 0.f, c11 = 0.f;
    __syncthreads();

    for (int ts = 0; ts < T_DIM; ++ts) {
        // ---- layer 0 gates: [x_t | h0] @ WT0, thread t computes f/o/g for hidden col t, both rows
        float af0 = 0.f, af1 = 0.f, ao0 = 0.f, ao1 = 0.f, ag0 = 0.f, ag1 = 0.f;
#pragma unroll 4
        for (int k = 0; k < K_DIM; ++k) {
            float s0 = xh0[0][k], s1 = xh0[1][k];
            float wf = WT0[k * G3 + t], wo = WT0[k * G3 + 256 + t], wg = WT0[k * G3 + 512 + t];
            af0 += wf * s0; af1 += wf * s1;
            ao0 += wo * s0; ao1 += wo * s1;
            ag0 += wg * s0; ag1 += wg * s1;
        }
        {
            float f0 = sigm(af0 + l0bf), f1 = sigm(af1 + l0bf);
            float o0 = sigm(ao0 + l0bo), o1 = sigm(ao1 + l0bo);
            float g0 = tanh_fast(ag0 + l0bg), g1 = tanh_fast(ag1 + l0bg);
            c00 = f0 * c00 + ig00 * g0; c01 = f1 * c01 + ig01 * g1;
            float h00 = o0 * tanh_fast(c00), h01 = o1 * tanh_fast(c01);
            __syncthreads();                                   // S1: gemm0 reads done
            xh0[0][I_DIM + t] = h00; xh0[1][I_DIM + t] = h01;
        }
        if (ts + 1 < T_DIM && t < 64) {                        // stage x_{t+1}
            int row = t >> 5, i = t & 31;
            xh0[row][i] = x[(r0 + row) * (T_DIM * I_DIM) + (ts + 1) * I_DIM + i];
        }
        __syncthreads();                                       // S2: h0_t visible
        // ---- projection inp1 = h0_t @ Wp0^T + bp0 (k-split across the 4 waves)
        {
            int lane = t & 63, w = t >> 6;
            int row = lane >> 5, i = lane & 31;
            float acc = 0.f;
            int k0 = w * 64;
            for (int h = k0; h < k0 + 64; ++h) acc += xh0[row][I_DIM + h] * WpT[h * I_DIM + i];
            pbuf[w][lane] = acc;
        }
        __syncthreads();                                       // S3
        if (t < 64) {
            int row = t >> 5, i = t & 31;
            xh1[row][i] = pbuf[0][t] + pbuf[1][t] + pbuf[2][t] + pbuf[3][t] + bp0[i];
        }
        __syncthreads();                                       // S4: inp1 visible
        // ---- layer 1 gates
        af0 = 0.f; af1 = 0.f; ao0 = 0.f; ao1 = 0.f; ag0 = 0.f; ag1 = 0.f;
#pragma unroll 4
        for (int k = 0; k < K_DIM; ++k) {
            float s0 = xh1[0][k], s1 = xh1[1][k];
            float wf = WT1[k * G3 + t], wo = WT1[k * G3 + 256 + t], wg = WT1[k * G3 + 512 + t];
            af0 += wf * s0; af1 += wf * s1;
            ao0 += wo * s0; ao1 += wo * s1;
            ag0 += wg * s0; ag1 += wg * s1;
        }
        {
            float f0 = sigm(af0 + l1bf), f1 = sigm(af1 + l1bf);
            float o0 = sigm(ao0 + l1bo), o1 = sigm(ao1 + l1bo);
            float g0 = tanh_fast(ag0 + l1bg), g1 = tanh_fast(ag1 + l1bg);
            c10 = f0 * c10 + ig10 * g0; c11 = f1 * c11 + ig11 * g1;
            float h10 = o0 * tanh_fast(c10), h11 = o1 * tanh_fast(c11);
            __syncthreads();                                   // S5: gemm1 reads done
            xh1[0][I_DIM + t] = h10; xh1[1][I_DIM + t] = h11;
        }
        // visibility for next iteration's gemm1 is provided by S1..S4 of next iter
    }
    __syncthreads();                                           // final h1 visible

    // ---- heads: out = relu(h1 @ Wh1^T + bh1) @ Wh2^T + bh2  +  future head
    if (t < 2 * FL_DIM) { int row = t / FL_DIM, k2 = t % FL_DIM; futs[row][k2] = future[(r0 + row) * FL_DIM + k2]; }
    float a0 = bh1[t], a1 = bh1[t];
    for (int h = 0; h < H_DIM; ++h) {
        float w = Wh1T[h * H_DIM + t];
        a0 += w * xh1[0][I_DIM + h]; a1 += w * xh1[1][I_DIM + h];
    }
    hidA[0][t] = fmaxf(a0, 0.f); hidA[1][t] = fmaxf(a1, 0.f);
    __syncthreads();                                           // futs + hidA visible
    float b0 = bf1[t], b1 = bf1[t];
    for (int k2 = 0; k2 < FL_DIM; ++k2) {
        float w = Wf1T[k2 * H_DIM + t];
        b0 += w * futs[0][k2]; b1 += w * futs[1][k2];
    }
    hidB[0][t] = fmaxf(b0, 0.f); hidB[1][t] = fmaxf(b1, 0.f);
    __syncthreads();
    if (t < 2 * L_DIM) {
        int row = t / L_DIM, l = t % L_DIM;
        float acc = bh2[l] + bf2[l];
        for (int j = 0; j < H_DIM; ++j)
            acc += hidA[row][j] * Wh2[l * H_DIM + j] + hidB[row][j] * Wf2[l * H_DIM + j];
        out[(r0 + row) * L_DIM + l] = acc;
    }
}

extern "C" void kernel_launch(void* const* d_in, const int* in_sizes, int n_in,
                              void* d_out, int out_size, void* d_ws, size_t ws_size,
                              hipStream_t stream) {
    const float* x    = (const float*)d_in[0];
    const float* stat = (const float*)d_in[1];
    const float* fut  = (const float*)d_in[2];
    const float* Wsh0 = (const float*)d_in[3];
    const float* bsh0 = (const float*)d_in[4];
    const float* Wdg0 = (const float*)d_in[5];
    const float* bdg0 = (const float*)d_in[6];
    const float* Whg0 = (const float*)d_in[7];
    const float* Wsh1 = (const float*)d_in[8];
    const float* bsh1 = (const float*)d_in[9];
    const float* Wdg1 = (const float*)d_in[10];
    const float* bdg1 = (const float*)d_in[11];
    const float* Whg1 = (const float*)d_in[12];
    const float* Wp0  = (const float*)d_in[13];
    const float* bp0  = (const float*)d_in[14];
    const float* Wh1  = (const float*)d_in[15];
    const float* bh1  = (const float*)d_in[16];
    const float* Wh2  = (const float*)d_in[17];
    const float* bh2  = (const float*)d_in[18];
    const float* Wf1  = (const float*)d_in[19];
    const float* bf1  = (const float*)d_in[20];
    const float* Wf2  = (const float*)d_in[21];
    const float* bf2  = (const float*)d_in[22];

    float* ws   = (float*)d_ws;
    float* WT0  = ws;                  // 288*768 = 221184
    float* WT1  = WT0 + 221184;        // 221184
    float* WpT  = WT1 + 221184;        // 256*32 = 8192
    float* Wh1T = WpT + 8192;          // 256*256 = 65536
    float* Wf1T = Wh1T + 65536;        // 56*256 = 14336
    float* ig0  = Wf1T + 14336;        // 256*256
    float* ig1  = ig0 + 65536;         // 256*256   (total ~2.65 MB)

    k_cat_transpose<<<864, 256, 0, stream>>>(Wdg0, Whg0, WT0);
    k_cat_transpose<<<864, 256, 0, stream>>>(Wdg1, Whg1, WT1);
    k_transpose<<<32, 256, 0, stream>>>(Wp0, WpT, I_DIM, H_DIM);    // [32][256] -> [256][32]
    k_transpose<<<256, 256, 0, stream>>>(Wh1, Wh1T, H_DIM, H_DIM);  // [256][256] -> T
    k_transpose<<<56, 256, 0, stream>>>(Wf1, Wf1T, H_DIM, FL_DIM);  // [256][56] -> [56][256]
    k_igate<<<B_DIM, 256, 0, stream>>>(stat, Wsh0, bsh0, ig0);
    k_igate<<<B_DIM, 256, 0, stream>>>(stat, Wsh1, bsh1, ig1);
    k_main<<<B_DIM / 2, 256, 0, stream>>>(x, fut, WT0, WT1, bdg0, bdg1, ig0, ig1,
                                          WpT, bp0, Wh1T, bh1, Wh2, bh2, Wf1T, bf1, Wf2, bf2,
                                          (float*)d_out);
}

// Round 2
// 3840.977 us; speedup vs baseline: 2.5554x; 2.5554x over previous
//
#include <hip/hip_runtime.h>
#include <math.h>

#define B_DIM 256
#define T_DIM 365
#define I_DIM 32
#define H_DIM 256
#define S_DIM 27
#define L_DIM 7
#define FL_DIM 56
#define G3 768
#define K_DIM 288
#define K2_DIM 144   // K_DIM/2 f16 pairs

typedef __attribute__((ext_vector_type(2))) _Float16 half2v;

__device__ __forceinline__ float fast_rcp(float x) { return __builtin_amdgcn_rcpf(x); }
__device__ __forceinline__ float sigm(float x) { return fast_rcp(1.0f + __expf(-x)); }
__device__ __forceinline__ float tanh_fast(float x) { return 1.0f - 2.0f * fast_rcp(1.0f + __expf(2.0f * x)); }

__device__ __forceinline__ float dot2(uint w, uint s, float acc) {
#if __has_builtin(__builtin_amdgcn_fdot2)
    return __builtin_amdgcn_fdot2(__builtin_bit_cast(half2v, w), __builtin_bit_cast(half2v, s), acc, false);
#else
    half2v a = __builtin_bit_cast(half2v, w), b = __builtin_bit_cast(half2v, s);
    return acc + (float)a.x * (float)b.x + (float)a.y * (float)b.y;
#endif
}

__device__ __forceinline__ ushort f16bits(float v) {
    _Float16 h = (_Float16)v;
    return __builtin_bit_cast(ushort, h);
}

// WTh[k2*G3+g] = pack_f16(W[g][2k2], W[g][2k2+1]); W[g][k] = k<I ? Wdg[g][k] : Whg[g][k-I]
__global__ void k_pack_w(const float* __restrict__ Wdg, const float* __restrict__ Whg,
                         uint* __restrict__ WTh) {
    int idx = blockIdx.x * 256 + threadIdx.x;      // over K2_DIM*G3
    if (idx >= K2_DIM * G3) return;
    int k2 = idx / G3, g = idx % G3;
    int k0 = 2 * k2, k1 = 2 * k2 + 1;
    float w0 = (k0 < I_DIM) ? Wdg[g * I_DIM + k0] : Whg[g * H_DIM + (k0 - I_DIM)];
    float w1 = (k1 < I_DIM) ? Wdg[g * I_DIM + k1] : Whg[g * H_DIM + (k1 - I_DIM)];
    half2v p; p.x = (_Float16)w0; p.y = (_Float16)w1;
    WTh[idx] = __builtin_bit_cast(uint, p);
}

__global__ void k_transpose(const float* __restrict__ in, float* __restrict__ out, int M, int N) {
    int idx = blockIdx.x * 256 + threadIdx.x;
    if (idx >= M * N) return;
    int n = idx / M, m = idx % M;
    out[idx] = in[m * N + n];
}

__global__ void k_igate(const float* __restrict__ st, const float* __restrict__ Wsh,
                        const float* __restrict__ bsh, float* __restrict__ ig) {
    __shared__ float s[S_DIM];
    int b = blockIdx.x, h = threadIdx.x;
    if (h < S_DIM) s[h] = st[b * S_DIM + h];
    __syncthreads();
    float a = bsh[h];
    for (int k = 0; k < S_DIM; ++k) a += s[k] * Wsh[h * S_DIM + k];
    ig[b * H_DIM + h] = sigm(a);
}

// Persistent kernel: block = 2 batch rows, 768 threads (12 waves).
// Gemm phase: thread g in [0,768) computes gate-column g preact for both rows via fp16 dot2.
// Update phase: threads 0-255 own hidden col, keep c in regs.
__global__ __launch_bounds__(768) void k_main(
    const float* __restrict__ x, const float* __restrict__ future,
    const uint* __restrict__ WTh0, const uint* __restrict__ WTh1,
    const float* __restrict__ bdg0, const float* __restrict__ bdg1,
    const float* __restrict__ ig0, const float* __restrict__ ig1,
    const float* __restrict__ WpT, const float* __restrict__ bp0,
    const float* __restrict__ Wh1T, const float* __restrict__ bh1,
    const float* __restrict__ Wh2, const float* __restrict__ bh2,
    const float* __restrict__ Wf1T, const float* __restrict__ bf1,
    const float* __restrict__ Wf2, const float* __restrict__ bf2,
    float* __restrict__ out) {
    __shared__ uint2 xq0[K2_DIM];          // per k2 pair: .x = row0 f16x2, .y = row1 f16x2
    __shared__ uint2 xq1[K2_DIM];
    __shared__ float pre0[3][2][H_DIM];    // layer0 gate preacts [which][row][col]
    __shared__ float pre1[3][2][H_DIM];
    __shared__ float hbuf[2][H_DIM];       // h0 fp32 (for projection)
    __shared__ float hbuf1[2][H_DIM];      // h1 fp32 (for heads)
    __shared__ float pbuf[4][64];
    __shared__ float futs[2][FL_DIM];

    const int t = threadIdx.x;
    const int r0 = blockIdx.x * 2;
    ushort* xq0h = (ushort*)xq0;
    ushort* xq1h = (ushort*)xq1;

    if (t < K2_DIM) { xq0[t] = make_uint2(0u, 0u); xq1[t] = make_uint2(0u, 0u); }
    __syncthreads();
    if (t < 64) {                                    // stage x_0
        int row = t >> 5, i = t & 31;
        float v = x[(r0 + row) * (T_DIM * I_DIM) + i];
        xq0h[(i >> 1) * 4 + row * 2 + (i & 1)] = f16bits(v);
    }
    const float bia0 = bdg0[t], bia1 = bdg1[t];
    float ig00 = 0.f, ig01 = 0.f, ig10 = 0.f, ig11 = 0.f;
    float c00 = 0.f, c01 = 0.f, c10 = 0.f, c11 = 0.f;
    if (t < H_DIM) {
        ig00 = ig0[(r0 + 0) * H_DIM + t]; ig01 = ig0[(r0 + 1) * H_DIM + t];
        ig10 = ig1[(r0 + 0) * H_DIM + t]; ig11 = ig1[(r0 + 1) * H_DIM + t];
    }
    const int col = t & 255, which = t >> 8;
    const uint* w0p = WTh0 + t;
    const uint* w1p = WTh1 + t;
    __syncthreads();

    for (int ts = 0; ts < T_DIM; ++ts) {
        // ---- layer-0 gates
        float a0 = bia0, a1 = bia0;
#pragma unroll 8
        for (int k2 = 0; k2 < K2_DIM; ++k2) {
            uint2 s = xq0[k2];
            uint w = w0p[k2 * G3];
            a0 = dot2(w, s.x, a0);
            a1 = dot2(w, s.y, a1);
        }
        pre0[which][0][col] = a0; pre0[which][1][col] = a1;
        __syncthreads();                                     // S1
        // ---- cell update 0 (t<256) + stage x_{t+1} (threads 512..575)
        if (t < H_DIM) {
            float f0 = sigm(pre0[0][0][t]), f1 = sigm(pre0[0][1][t]);
            float o0 = sigm(pre0[1][0][t]), o1 = sigm(pre0[1][1][t]);
            float g0 = tanh_fast(pre0[2][0][t]), g1 = tanh_fast(pre0[2][1][t]);
            c00 = f0 * c00 + ig00 * g0; c01 = f1 * c01 + ig01 * g1;
            float h00 = o0 * tanh_fast(c00), h01 = o1 * tanh_fast(c01);
            hbuf[0][t] = h00; hbuf[1][t] = h01;
            int k = I_DIM + t, k2 = k >> 1;
            xq0h[k2 * 4 + (k & 1)] = f16bits(h00);
            xq0h[k2 * 4 + 2 + (k & 1)] = f16bits(h01);
        } else if (t >= 512 && t < 576 && ts + 1 < T_DIM) {
            int tt = t - 512, row = tt >> 5, i = tt & 31;
            float v = x[(r0 + row) * (T_DIM * I_DIM) + (ts + 1) * I_DIM + i];
            xq0h[(i >> 1) * 4 + row * 2 + (i & 1)] = f16bits(v);
        }
        __syncthreads();                                     // S2
        // ---- projection partials (threads 256..511): inp1 = h0 @ Wp0^T + bp0
        if (t >= 256 && t < 512) {
            int t2 = t - 256, i = t2 & 63, slice = t2 >> 6;
            int row = i >> 5, cp = i & 31;
            const float* hb = hbuf[row];
            const float* wp = WpT + cp;
            float acc = 0.f;
            int h0i = slice * 64;
#pragma unroll 8
            for (int h = h0i; h < h0i + 64; ++h) acc += hb[h] * wp[h * I_DIM];
            pbuf[slice][i] = acc;
        }
        __syncthreads();                                     // S3
        if (t < 32) {
            int row = t >> 4, jp = t & 15;
            int i0 = row * 32 + 2 * jp, i1 = i0 + 1;
            float v0 = pbuf[0][i0] + pbuf[1][i0] + pbuf[2][i0] + pbuf[3][i0] + bp0[2 * jp];
            float v1 = pbuf[0][i1] + pbuf[1][i1] + pbuf[2][i1] + pbuf[3][i1] + bp0[2 * jp + 1];
            half2v p; p.x = (_Float16)v0; p.y = (_Float16)v1;
            ((uint*)xq1)[jp * 2 + row] = __builtin_bit_cast(uint, p);
        }
        __syncthreads();                                     // S4
        // ---- layer-1 gates
        a0 = bia1; a1 = bia1;
#pragma unroll 8
        for (int k2 = 0; k2 < K2_DIM; ++k2) {
            uint2 s = xq1[k2];
            uint w = w1p[k2 * G3];
            a0 = dot2(w, s.x, a0);
            a1 = dot2(w, s.y, a1);
        }
        pre1[which][0][col] = a0; pre1[which][1][col] = a1;
        __syncthreads();                                     // S5
        if (t < H_DIM) {
            float f0 = sigm(pre1[0][0][t]), f1 = sigm(pre1[0][1][t]);
            float o0 = sigm(pre1[1][0][t]), o1 = sigm(pre1[1][1][t]);
            float g0 = tanh_fast(pre1[2][0][t]), g1 = tanh_fast(pre1[2][1][t]);
            c10 = f0 * c10 + ig10 * g0; c11 = f1 * c11 + ig11 * g1;
            float h10 = o0 * tanh_fast(c10), h11 = o1 * tanh_fast(c11);
            hbuf1[0][t] = h10; hbuf1[1][t] = h11;
            int k = I_DIM + t, k2 = k >> 1;
            xq1h[k2 * 4 + (k & 1)] = f16bits(h10);
            xq1h[k2 * 4 + 2 + (k & 1)] = f16bits(h11);
        }
        // no barrier needed: next-iter threads touch xq0/pre0 only until S4
    }
    __syncthreads();

    // ---- heads
    if (t < 2 * FL_DIM) { int row = t / FL_DIM, k = t % FL_DIM; futs[row][k] = future[(r0 + row) * FL_DIM + k]; }
    if (t < H_DIM) {
        float a0 = bh1[t], a1 = bh1[t];
        for (int h = 0; h < H_DIM; ++h) {
            float w = Wh1T[h * H_DIM + t];
            a0 += w * hbuf1[0][h]; a1 += w * hbuf1[1][h];
        }
        pre0[0][0][t] = fmaxf(a0, 0.f); pre0[0][1][t] = fmaxf(a1, 0.f);
    }
    __syncthreads();
    if (t < H_DIM) {
        float b0 = bf1[t], b1 = bf1[t];
        for (int k = 0; k < FL_DIM; ++k) {
            float w = Wf1T[k * H_DIM + t];
            b0 += w * futs[0][k]; b1 += w * futs[1][k];
        }
        pre0[1][0][t] = fmaxf(b0, 0.f); pre0[1][1][t] = fmaxf(b1, 0.f);
    }
    __syncthreads();
    if (t < 2 * L_DIM) {
        int row = t / L_DIM, l = t % L_DIM;
        float acc = bh2[l] + bf2[l];
        for (int j = 0; j < H_DIM; ++j)
            acc += pre0[0][row][j] * Wh2[l * H_DIM + j] + pre0[1][row][j] * Wf2[l * H_DIM + j];
        out[(r0 + row) * L_DIM + l] = acc;
    }
}

extern "C" void kernel_launch(void* const* d_in, const int* in_sizes, int n_in,
                              void* d_out, int out_size, void* d_ws, size_t ws_size,
                              hipStream_t stream) {
    const float* x    = (const float*)d_in[0];
    const float* stat = (const float*)d_in[1];
    const float* fut  = (const float*)d_in[2];
    const float* Wsh0 = (const float*)d_in[3];
    const float* bsh0 = (const float*)d_in[4];
    const float* Wdg0 = (const float*)d_in[5];
    const float* bdg0 = (const float*)d_in[6];
    const float* Whg0 = (const float*)d_in[7];
    const float* Wsh1 = (const float*)d_in[8];
    const float* bsh1 = (const float*)d_in[9];
    const float* Wdg1 = (const float*)d_in[10];
    const float* bdg1 = (const float*)d_in[11];
    const float* Whg1 = (const float*)d_in[12];
    const float* Wp0  = (const float*)d_in[13];
    const float* bp0  = (const float*)d_in[14];
    const float* Wh1  = (const float*)d_in[15];
    const float* bh1  = (const float*)d_in[16];
    const float* Wh2  = (const float*)d_in[17];
    const float* bh2  = (const float*)d_in[18];
    const float* Wf1  = (const float*)d_in[19];
    const float* bf1  = (const float*)d_in[20];
    const float* Wf2  = (const float*)d_in[21];
    const float* bf2  = (const float*)d_in[22];

    float* ws   = (float*)d_ws;
    uint*  WTh0 = (uint*)ws;                 // 144*768 dwords
    uint*  WTh1 = WTh0 + K2_DIM * G3;        // 144*768
    float* WpT  = (float*)(WTh1 + K2_DIM * G3);  // 256*32
    float* Wh1T = WpT + H_DIM * I_DIM;       // 256*256
    float* Wf1T = Wh1T + H_DIM * H_DIM;      // 56*256
    float* ig0  = Wf1T + FL_DIM * H_DIM;     // 256*256
    float* ig1  = ig0 + B_DIM * H_DIM;       // 256*256

    k_pack_w<<<(K2_DIM * G3 + 255) / 256, 256, 0, stream>>>(Wdg0, Whg0, WTh0);
    k_pack_w<<<(K2_DIM * G3 + 255) / 256, 256, 0, stream>>>(Wdg1, Whg1, WTh1);
    k_transpose<<<(I_DIM * H_DIM + 255) / 256, 256, 0, stream>>>(Wp0, WpT, I_DIM, H_DIM);
    k_transpose<<<(H_DIM * H_DIM + 255) / 256, 256, 0, stream>>>(Wh1, Wh1T, H_DIM, H_DIM);
    k_transpose<<<(H_DIM * FL_DIM + 255) / 256, 256, 0, stream>>>(Wf1, Wf1T, H_DIM, FL_DIM);
    k_igate<<<B_DIM, H_DIM, 0, stream>>>(stat, Wsh0, bsh0, ig0);
    k_igate<<<B_DIM, H_DIM, 0, stream>>>(stat, Wsh1, bsh1, ig1);
    k_main<<<B_DIM / 2, 768, 0, stream>>>(x, fut, WTh0, WTh1, bdg0, bdg1, ig0, ig1,
                                          WpT, bp0, Wh1T, bh1, Wh2, bh2, Wf1T, bf1, Wf2, bf2,
                                          (float*)d_out);
}

// Round 3
// 3571.733 us; speedup vs baseline: 2.7481x; 1.0754x over previous
//
#include <hip/hip_runtime.h>
#include <math.h>

#define B_DIM 256
#define T_DIM 365
#define I_DIM 32
#define H_DIM 256
#define S_DIM 27
#define L_DIM 7
#define FL_DIM 56
#define G3 768
#define NC_A0 36   // uint4 chunks for [x|h0] (K=288 -> K2=144 -> 36)
#define NC_A1 32   // uint4 chunks for h1 (K=256 -> K2=128 -> 32)
#define NC_A  68
#define NC_B  4    // uint4 chunks for inp1 (K=32 -> K2=16 -> 4)

typedef __attribute__((ext_vector_type(2))) _Float16 half2v;

__device__ __forceinline__ float fast_rcp(float x) { return __builtin_amdgcn_rcpf(x); }
__device__ __forceinline__ float sigm(float x) { return fast_rcp(1.0f + __expf(-x)); }
__device__ __forceinline__ float tanh_fast(float x) { return 1.0f - 2.0f * fast_rcp(1.0f + __expf(2.0f * x)); }

__device__ __forceinline__ float dot2(uint w, uint s, float acc) {
#if __has_builtin(__builtin_amdgcn_fdot2)
    return __builtin_amdgcn_fdot2(__builtin_bit_cast(half2v, w), __builtin_bit_cast(half2v, s), acc, false);
#else
    half2v a = __builtin_bit_cast(half2v, w), b = __builtin_bit_cast(half2v, s);
    return acc + (float)a.x * (float)b.x + (float)a.y * (float)b.y;
#endif
}

__device__ __forceinline__ ushort f16bits(float v) {
    _Float16 h = (_Float16)v;
    return __builtin_bit_cast(ushort, h);
}

// WA layout: uint idx = ((c*G3)+g)*4 + j ; chunk c<36: k2=4c+j over [x|h0] layer0 weights,
// c>=36: k2=4(c-36)+j over Whg1. Value = f16x2(W[g][2k2], W[g][2k2+1]).
__global__ void k_pack_A(const float* __restrict__ Wdg0, const float* __restrict__ Whg0,
                         const float* __restrict__ Whg1, uint* __restrict__ WA) {
    int idx = blockIdx.x * 256 + threadIdx.x;
    if (idx >= NC_A * G3 * 4) return;
    int j = idx & 3;
    int g = (idx >> 2) % G3;
    int c = idx / (4 * G3);
    float w0, w1;
    if (c < NC_A0) {
        int k2 = 4 * c + j;
        int k0 = 2 * k2, k1 = k0 + 1;
        w0 = (k0 < I_DIM) ? Wdg0[g * I_DIM + k0] : Whg0[g * H_DIM + (k0 - I_DIM)];
        w1 = (k1 < I_DIM) ? Wdg0[g * I_DIM + k1] : Whg0[g * H_DIM + (k1 - I_DIM)];
    } else {
        int k2 = 4 * (c - NC_A0) + j;
        int k0 = 2 * k2, k1 = k0 + 1;
        w0 = Whg1[g * H_DIM + k0];
        w1 = Whg1[g * H_DIM + k1];
    }
    half2v p; p.x = (_Float16)w0; p.y = (_Float16)w1;
    WA[idx] = __builtin_bit_cast(uint, p);
}

__global__ void k_pack_B(const float* __restrict__ Wdg1, uint* __restrict__ WB) {
    int idx = blockIdx.x * 256 + threadIdx.x;
    if (idx >= NC_B * G3 * 4) return;
    int j = idx & 3;
    int g = (idx >> 2) % G3;
    int c = idx / (4 * G3);
    int k2 = 4 * c + j;
    int k0 = 2 * k2, k1 = k0 + 1;
    half2v p; p.x = (_Float16)Wdg1[g * I_DIM + k0]; p.y = (_Float16)Wdg1[g * I_DIM + k1];
    WB[idx] = __builtin_bit_cast(uint, p);
}

__global__ void k_transpose(const float* __restrict__ in, float* __restrict__ out, int M, int N) {
    int idx = blockIdx.x * 256 + threadIdx.x;
    if (idx >= M * N) return;
    int n = idx / M, m = idx % M;
    out[idx] = in[m * N + n];
}

__global__ void k_igate(const float* __restrict__ st, const float* __restrict__ Wsh,
                        const float* __restrict__ bsh, float* __restrict__ ig) {
    __shared__ float s[S_DIM];
    int b = blockIdx.x, h = threadIdx.x;
    if (h < S_DIM) s[h] = st[b * S_DIM + h];
    __syncthreads();
    float a = bsh[h];
    for (int k = 0; k < S_DIM; ++k) a += s[k] * Wsh[h * S_DIM + k];
    ig[b * H_DIM + h] = sigm(a);
}

// Persistent kernel: block = 2 batch rows, 768 threads (12 waves).
// Phase A per step: thread g computes layer0 gate-col g over [x|h0] AND layer1 recurrent
// partial over h1_{t-1} (both rows), coalesced uint4 weight stream. Phase B adds the
// tiny K=32 inp1 contribution.
__global__ __launch_bounds__(768) void k_main(
    const float* __restrict__ x, const float* __restrict__ future,
    const uint* __restrict__ WA, const uint* __restrict__ WB,
    const float* __restrict__ bdg0, const float* __restrict__ bdg1,
    const float* __restrict__ ig0, const float* __restrict__ ig1,
    const float* __restrict__ WpT, const float* __restrict__ bp0,
    const float* __restrict__ Wh1T, const float* __restrict__ bh1,
    const float* __restrict__ Wh2, const float* __restrict__ bh2,
    const float* __restrict__ Wf1T, const float* __restrict__ bf1,
    const float* __restrict__ Wf2, const float* __restrict__ bf2,
    float* __restrict__ out) {
    __shared__ uint4 xr0A[NC_A0], xr1A[NC_A0];   // [x_t | h0] f16x2 per row
    __shared__ uint4 hr0[NC_A1], hr1[NC_A1];     // h1 f16x2 per row
    __shared__ uint4 xq1x0[NC_B], xq1x1[NC_B];   // inp1 f16x2 per row
    __shared__ float pre0[3][2][H_DIM];
    __shared__ float pre1[3][2][H_DIM];
    __shared__ float hbuf[2][H_DIM];             // h0 fp32
    __shared__ float hbuf1[2][H_DIM];            // h1 fp32
    __shared__ float pbuf[4][64];
    __shared__ float futs[2][FL_DIM];

    const int t = threadIdx.x;
    const int r0 = blockIdx.x * 2;

    uint4 u4z = make_uint4(0u, 0u, 0u, 0u);
    if (t < NC_A0) { xr0A[t] = u4z; xr1A[t] = u4z; }
    if (t < NC_A1) { hr0[t] = u4z; hr1[t] = u4z; }
    __syncthreads();
    if (t < 64) {                                  // stage x_0
        int row = t >> 5, i = t & 31;
        float v = x[(r0 + row) * (T_DIM * I_DIM) + i];
        if (row == 0) ((ushort*)xr0A)[i] = f16bits(v);
        else          ((ushort*)xr1A)[i] = f16bits(v);
    }
    const float bia0 = bdg0[t], bia1 = bdg1[t];
    float ig00 = 0.f, ig01 = 0.f, ig10 = 0.f, ig11 = 0.f;
    float c00 = 0.f, c01 = 0.f, c10 = 0.f, c11 = 0.f;
    if (t < H_DIM) {
        ig00 = ig0[(r0 + 0) * H_DIM + t]; ig01 = ig0[(r0 + 1) * H_DIM + t];
        ig10 = ig1[(r0 + 0) * H_DIM + t]; ig11 = ig1[(r0 + 1) * H_DIM + t];
    }
    const int col = t & 255, which = t >> 8;
    __syncthreads();

    for (int ts = 0; ts < T_DIM; ++ts) {
        // ---- Phase A: big gemm (layer0 full K + layer1 recurrent K)
        float a0 = bia0, a1 = bia0;
        float b0 = bia1, b1 = bia1;
        {
            const uint4* wa = (const uint4*)WA + t;
#pragma unroll 8
            for (int c = 0; c < NC_A0; ++c) {
                uint4 w = wa[c * G3];
                uint4 s0 = xr0A[c], s1 = xr1A[c];
                a0 = dot2(w.x, s0.x, a0); a1 = dot2(w.x, s1.x, a1);
                a0 = dot2(w.y, s0.y, a0); a1 = dot2(w.y, s1.y, a1);
                a0 = dot2(w.z, s0.z, a0); a1 = dot2(w.z, s1.z, a1);
                a0 = dot2(w.w, s0.w, a0); a1 = dot2(w.w, s1.w, a1);
            }
            const uint4* wh = (const uint4*)WA + NC_A0 * G3 + t;
#pragma unroll 8
            for (int c = 0; c < NC_A1; ++c) {
                uint4 w = wh[c * G3];
                uint4 s0 = hr0[c], s1 = hr1[c];
                b0 = dot2(w.x, s0.x, b0); b1 = dot2(w.x, s1.x, b1);
                b0 = dot2(w.y, s0.y, b0); b1 = dot2(w.y, s1.y, b1);
                b0 = dot2(w.z, s0.z, b0); b1 = dot2(w.z, s1.z, b1);
                b0 = dot2(w.w, s0.w, b0); b1 = dot2(w.w, s1.w, b1);
            }
        }
        pre0[which][0][col] = a0; pre0[which][1][col] = a1;
        __syncthreads();                               // S1
        // ---- update 0 (t<256) + stage x_{t+1}
        if (t < H_DIM) {
            float f0 = sigm(pre0[0][0][t]), f1 = sigm(pre0[0][1][t]);
            float o0 = sigm(pre0[1][0][t]), o1 = sigm(pre0[1][1][t]);
            float g0 = tanh_fast(pre0[2][0][t]), g1 = tanh_fast(pre0[2][1][t]);
            c00 = f0 * c00 + ig00 * g0; c01 = f1 * c01 + ig01 * g1;
            float h00 = o0 * tanh_fast(c00), h01 = o1 * tanh_fast(c01);
            hbuf[0][t] = h00; hbuf[1][t] = h01;
            ((ushort*)xr0A)[I_DIM + t] = f16bits(h00);
            ((ushort*)xr1A)[I_DIM + t] = f16bits(h01);
        } else if (t >= 512 && t < 576 && ts + 1 < T_DIM) {
            int tt = t - 512, row = tt >> 5, i = tt & 31;
            float v = x[(r0 + row) * (T_DIM * I_DIM) + (ts + 1) * I_DIM + i];
            if (row == 0) ((ushort*)xr0A)[i] = f16bits(v);
            else          ((ushort*)xr1A)[i] = f16bits(v);
        }
        __syncthreads();                               // S2
        // ---- projection partials (threads 256..511)
        if (t >= 256 && t < 512) {
            int t2 = t - 256, i = t2 & 63, slice = t2 >> 6;
            int row = i >> 5, cp = i & 31;
            const float* hb = hbuf[row];
            const float* wp = WpT + cp;
            float acc = 0.f;
            int h0i = slice * 64;
#pragma unroll 8
            for (int h = h0i; h < h0i + 64; ++h) acc += hb[h] * wp[h * I_DIM];
            pbuf[slice][i] = acc;
        }
        __syncthreads();                               // S3
        if (t < 32) {
            int row = t >> 4, jp = t & 15;
            int i0 = row * 32 + 2 * jp, i1 = i0 + 1;
            float v0 = pbuf[0][i0] + pbuf[1][i0] + pbuf[2][i0] + pbuf[3][i0] + bp0[2 * jp];
            float v1 = pbuf[0][i1] + pbuf[1][i1] + pbuf[2][i1] + pbuf[3][i1] + bp0[2 * jp + 1];
            half2v p; p.x = (_Float16)v0; p.y = (_Float16)v1;
            uint pw = __builtin_bit_cast(uint, p);
            if (row == 0) ((uint*)xq1x0)[jp] = pw;
            else          ((uint*)xq1x1)[jp] = pw;
        }
        __syncthreads();                               // S4
        // ---- Phase B: tiny inp1 gemm (K=32), accumulate onto carried b0/b1
        {
            const uint4* wb = (const uint4*)WB + t;
#pragma unroll 4
            for (int c = 0; c < NC_B; ++c) {
                uint4 w = wb[c * G3];
                uint4 s0 = xq1x0[c], s1 = xq1x1[c];
                b0 = dot2(w.x, s0.x, b0); b1 = dot2(w.x, s1.x, b1);
                b0 = dot2(w.y, s0.y, b0); b1 = dot2(w.y, s1.y, b1);
                b0 = dot2(w.z, s0.z, b0); b1 = dot2(w.z, s1.z, b1);
                b0 = dot2(w.w, s0.w, b0); b1 = dot2(w.w, s1.w, b1);
            }
        }
        pre1[which][0][col] = b0; pre1[which][1][col] = b1;
        __syncthreads();                               // S5
        // ---- update 1 (t<256)
        if (t < H_DIM) {
            float f0 = sigm(pre1[0][0][t]), f1 = sigm(pre1[0][1][t]);
            float o0 = sigm(pre1[1][0][t]), o1 = sigm(pre1[1][1][t]);
            float g0 = tanh_fast(pre1[2][0][t]), g1 = tanh_fast(pre1[2][1][t]);
            c10 = f0 * c10 + ig10 * g0; c11 = f1 * c11 + ig11 * g1;
            float h10 = o0 * tanh_fast(c10), h11 = o1 * tanh_fast(c11);
            hbuf1[0][t] = h10; hbuf1[1][t] = h11;
            ((ushort*)hr0)[t] = f16bits(h10);
            ((ushort*)hr1)[t] = f16bits(h11);
        }
        __syncthreads();                               // S6 (h1 visible to next Phase A)
    }

    // ---- heads
    if (t < 2 * FL_DIM) { int row = t / FL_DIM, k = t % FL_DIM; futs[row][k] = future[(r0 + row) * FL_DIM + k]; }
    if (t < H_DIM) {
        float a0 = bh1[t], a1 = bh1[t];
        for (int h = 0; h < H_DIM; ++h) {
            float w = Wh1T[h * H_DIM + t];
            a0 += w * hbuf1[0][h]; a1 += w * hbuf1[1][h];
        }
        pre0[0][0][t] = fmaxf(a0, 0.f); pre0[0][1][t] = fmaxf(a1, 0.f);
    }
    __syncthreads();
    if (t < H_DIM) {
        float b0 = bf1[t], b1 = bf1[t];
        for (int k = 0; k < FL_DIM; ++k) {
            float w = Wf1T[k * H_DIM + t];
            b0 += w * futs[0][k]; b1 += w * futs[1][k];
        }
        pre0[1][0][t] = fmaxf(b0, 0.f); pre0[1][1][t] = fmaxf(b1, 0.f);
    }
    __syncthreads();
    if (t < 2 * L_DIM) {
        int row = t / L_DIM, l = t % L_DIM;
        float acc = bh2[l] + bf2[l];
        for (int j = 0; j < H_DIM; ++j)
            acc += pre0[0][row][j] * Wh2[l * H_DIM + j] + pre0[1][row][j] * Wf2[l * H_DIM + j];
        out[(r0 + row) * L_DIM + l] = acc;
    }
}

extern "C" void kernel_launch(void* const* d_in, const int* in_sizes, int n_in,
                              void* d_out, int out_size, void* d_ws, size_t ws_size,
                              hipStream_t stream) {
    const float* x    = (const float*)d_in[0];
    const float* stat = (const float*)d_in[1];
    const float* fut  = (const float*)d_in[2];
    const float* Wsh0 = (const float*)d_in[3];
    const float* bsh0 = (const float*)d_in[4];
    const float* Wdg0 = (const float*)d_in[5];
    const float* bdg0 = (const float*)d_in[6];
    const float* Whg0 = (const float*)d_in[7];
    const float* Wsh1 = (const float*)d_in[8];
    const float* bsh1 = (const float*)d_in[9];
    const float* Wdg1 = (const float*)d_in[10];
    const float* bdg1 = (const float*)d_in[11];
    const float* Whg1 = (const float*)d_in[12];
    const float* Wp0  = (const float*)d_in[13];
    const float* bp0  = (const float*)d_in[14];
    const float* Wh1  = (const float*)d_in[15];
    const float* bh1  = (const float*)d_in[16];
    const float* Wh2  = (const float*)d_in[17];
    const float* bh2  = (const float*)d_in[18];
    const float* Wf1  = (const float*)d_in[19];
    const float* bf1  = (const float*)d_in[20];
    const float* Wf2  = (const float*)d_in[21];
    const float* bf2  = (const float*)d_in[22];

    float* ws   = (float*)d_ws;
    uint*  WA   = (uint*)ws;                      // 68*768*4 uints
    uint*  WB   = WA + NC_A * G3 * 4;             // 4*768*4
    float* WpT  = (float*)(WB + NC_B * G3 * 4);   // 256*32
    float* Wh1T = WpT + H_DIM * I_DIM;            // 256*256
    float* Wf1T = Wh1T + H_DIM * H_DIM;           // 56*256
    float* ig0  = Wf1T + FL_DIM * H_DIM;          // 256*256
    float* ig1  = ig0 + B_DIM * H_DIM;            // 256*256

    k_pack_A<<<(NC_A * G3 * 4 + 255) / 256, 256, 0, stream>>>(Wdg0, Whg0, Whg1, WA);
    k_pack_B<<<(NC_B * G3 * 4 + 255) / 256, 256, 0, stream>>>(Wdg1, WB);
    k_transpose<<<(I_DIM * H_DIM + 255) / 256, 256, 0, stream>>>(Wp0, WpT, I_DIM, H_DIM);
    k_transpose<<<(H_DIM * H_DIM + 255) / 256, 256, 0, stream>>>(Wh1, Wh1T, H_DIM, H_DIM);
    k_transpose<<<(H_DIM * FL_DIM + 255) / 256, 256, 0, stream>>>(Wf1, Wf1T, H_DIM, FL_DIM);
    k_igate<<<B_DIM, H_DIM, 0, stream>>>(stat, Wsh0, bsh0, ig0);
    k_igate<<<B_DIM, H_DIM, 0, stream>>>(stat, Wsh1, bsh1, ig1);
    k_main<<<B_DIM / 2, 768, 0, stream>>>(x, fut, WA, WB, bdg0, bdg1, ig0, ig1,
                                          WpT, bp0, Wh1T, bh1, Wh2, bh2, Wf1T, bf1, Wf2, bf2,
                                          (float*)d_out);
}